// Round 5
// baseline (653.805 us; speedup 1.0000x reference)
//
#include <hip/hip_runtime.h>
#include <hip/hip_bf16.h>

// Problem constants (fixed by reference): B=4, L=4096, R=8, DV=64
#define BB  4
#define LL  4096
#define RR  8
#define DVV 64

typedef __bf16 bf16x8 __attribute__((ext_vector_type(8)));
typedef __bf16 bf16x4 __attribute__((ext_vector_type(4)));
typedef float  f32x4  __attribute__((ext_vector_type(4)));
typedef int    i32x4  __attribute__((ext_vector_type(4)));

#define LGKM_BARRIER() \
  asm volatile("s_waitcnt lgkmcnt(0)\n\ts_barrier" ::: "memory")

// ---------------------------------------------------------------------------
// Pre-kernel (256 blocks x 256 thr): v[b][m][d] fp32 -> vF fragment-linear
// bf16 MFMA B-fragments (unit = (b, colblk32, dblk16); lane l holds
// V[colblk*32 + (l>>4)*8 + j][dblk*16 + (l&15)], 16B contiguous per lane).
// ---------------------------------------------------------------------------
__global__ __launch_bounds__(256) void prep_kernel(
    const float* __restrict__ v, __bf16* __restrict__ vF) {
  __shared__ __bf16 tl[64][72];
  const int blk = blockIdx.x;         // 256 blocks
  const int b   = blk >> 6;           // 64 tiles per batch
  const int m0  = (blk & 63) << 6;
  const int tid = threadIdx.x;

  const float* vb = v + (((size_t)(b * LL + m0)) << 6);
#pragma unroll
  for (int i = 0; i < 16; ++i) {
    const int idx = (i << 8) + tid;   // m = idx>>6, d = idx&63
    tl[idx & 63][idx >> 6] = (__bf16)vb[idx];
  }
  __syncthreads();

  const int wv = tid >> 6, ln = tid & 63;
#pragma unroll
  for (int i = 0; i < 2; ++i) {
    const int u  = wv + (i << 2);
    const int cb = u >> 2, gg = u & 3;
    const int d  = gg * 16 + (ln & 15);
    const int c  = cb * 32 + ((ln >> 4) << 3);
    const size_t unit = ((size_t)(b * 128 + (m0 >> 5) + cb) << 2) + gg;
    *(bf16x8*)(vF + (unit << 9) + (ln << 3)) = *(const bf16x8*)&tl[d][c];
  }
}

// ---------------------------------------------------------------------------
// Main kernel: 512 PERSISTENT WGs x 512 thr (2 WGs/CU, exact residency).
// Each WG owns (b, 4 consecutive 8-row blocks). Wave owns 512 cols; lane
// owns cols {W+lane*4, W+256+lane*4} (dense 1KB stores).
// KEY CHANGE vs round 4: attn stores for block j are deferred and trickled
// one-row-at-a-time into block j+1's SCORE phase (block 3's into its own PV
// loop). Previously stores were confined to the PV phase (~35% duty) ->
// store pipe idled during score -> 2.2 TB/s plateau (= 0.35 * 6.4 fill BW).
// Spreading issue across the whole kernel keeps the CU->L2 store queue fed
// continuously. All barriers are lgkm-only so in-flight stores are never
// drained; only the end-of-kernel drain remains (paid once, not 4x).
// Prev-block p is re-read from pbuf BEFORE the same row is overwritten
// (exact-alias read-before-write, single 64 KB buffer); epilogue osum lives
// in a separate 8 KB buffer (2-step cross-wave reduce) since pbuf must
// survive into the next score phase. LDS 74 KB -> 2 WGs/CU.
// ---------------------------------------------------------------------------
__global__ __launch_bounds__(512, 4) void attn_main(
    const float* __restrict__ ra1, const float* __restrict__ ra2,
    const int* __restrict__ mask, const __bf16* __restrict__ vF,
    float* __restrict__ out, float* __restrict__ attn) {
  __shared__ __bf16 pbuf[8 * 8 * 512];    // 64 KB: [wave][row][col] bf16 e
  __shared__ float  osum4[4 * 8 * 64];    // 8 KB: 2-step O reduction
  __shared__ float  red[8][8];            // [row][wave] partial row sums

  const int wg   = blockIdx.x;            // 0..511 (persistent)
  const int b    = wg >> 7;               // 128 WGs per batch
  const int blk0 = (wg & 127) << 2;       // first of 4 consecutive blocks
  const int tid  = threadIdx.x;
  const int wave = tid >> 6;              // 0..7
  const int lane = tid & 63;
  const int W    = wave << 9;             // wave's 512-col chunk
  const int lrow = lane & 15, kg = lane >> 4;
  const int lr8  = lrow & 7;              // A rows 8-15 duplicate rows 0-7

  // ---- one-time (per 4 blocks): ra2 (8r x 2x4 cols) + mask registers ----
  const float* r2 = ra2 + (size_t)b * (RR * LL) + W + (lane << 2);
  f32x4 rA[RR], rB[RR];
#pragma unroll
  for (int r = 0; r < RR; ++r) {
    rA[r] = *(const f32x4*)(r2 + r * LL);
    rB[r] = *(const f32x4*)(r2 + r * LL + 256);
  }
  const int* mp = mask + (size_t)b * LL + W + (lane << 2);   // mask [B][1][L]
  const i32x4 mAv = *(const i32x4*)mp;
  const i32x4 mBv = *(const i32x4*)(mp + 256);
  f32x4 mA, mB;
#pragma unroll
  for (int j = 0; j < 4; ++j) {
    mA[j] = mAv[j] ? 1.0f : 0.0f;
    mB[j] = mBv[j] ? 1.0f : 0.0f;
  }

  char* const   pw  = (char*)pbuf + (wave << 13);   // wave's 8 KB slice
  const __bf16* vFb = vF + ((size_t)b << 18);

  float  rinv[8];           // row 1/sum: consumed for block j-1, then rewritten
  float* attn_prev = nullptr;

#pragma unroll 1
  for (int jj = 0; jj < 4; ++jj) {
    const int row0 = (blk0 + jj) << 3;
    const float* a_base  = ra1 + ((size_t)b * LL + row0) * RR;
    float* attn_cur = attn + ((size_t)b * LL + row0) * LL + W + (lane << 2);
    const bool have_prev = (jj > 0);

    // ---- score phase for block jj, interleaved with block jj-1 stores ----
    float part[8];
#pragma unroll
    for (int i = 0; i < 8; ++i) {
      const int swz  = i << 4;
      char* pposA = pw + (i << 10) + (((lane << 3)) ^ swz);
      char* pposB = pw + (i << 10) + ((512 + (lane << 3)) ^ swz);

      if (have_prev) {   // trickle one 2KB row-store of the previous block
        const bf16x4 qA = *(const bf16x4*)pposA;   // read BEFORE overwrite
        const bf16x4 qB = *(const bf16x4*)pposB;
        f32x4 oA, oB;
#pragma unroll
        for (int j = 0; j < 4; ++j) {
          oA[j] = (float)qA[j] * rinv[i];
          oB[j] = (float)qB[j] * rinv[i];
        }
        *(f32x4*)(attn_prev + (size_t)i * LL)       = oA;
        *(f32x4*)(attn_prev + (size_t)i * LL + 256) = oB;
        __builtin_amdgcn_sched_barrier(0);   // pin pacing: no store clustering
      }

      const float* ap = a_base + i * RR;   // row-uniform -> scalar loads
      f32x4 sA = {0.f, 0.f, 0.f, 0.f}, sB = {0.f, 0.f, 0.f, 0.f};
#pragma unroll
      for (int r = 0; r < RR; ++r) {
        const float a = ap[r];
#pragma unroll
        for (int j = 0; j < 4; ++j) {
          sA[j] = fmaf(a, rA[r][j], sA[j]);
          sB[j] = fmaf(a, rB[r][j], sB[j]);
        }
      }
      f32x4 eA, eB;
#pragma unroll
      for (int j = 0; j < 4; ++j) {
        eA[j] = __expf(sA[j]) * mA[j];   // |s| <= ~17: exp safe in fp32
        eB[j] = __expf(sB[j]) * mB[j];
      }
      part[i] = ((eA[0] + eA[1]) + (eA[2] + eA[3])) +
                ((eB[0] + eB[1]) + (eB[2] + eB[3]));

      bf16x4 pA, pB;
#pragma unroll
      for (int j = 0; j < 4; ++j) { pA[j] = (__bf16)eA[j]; pB[j] = (__bf16)eB[j]; }
      *(bf16x4*)pposA = pA;
      *(bf16x4*)pposB = pB;
    }

    // 8 independent butterfly chains, interleaved -> latency pipelined
#pragma unroll
    for (int s = 1; s < 64; s <<= 1)
#pragma unroll
      for (int i = 0; i < 8; ++i) part[i] += __shfl_xor(part[i], s);
    if (lane == 0) {
#pragma unroll
      for (int i = 0; i < 8; ++i) red[i][wave] = part[i];
    }
    LGKM_BARRIER();   // lgkm-only: deferred stores stay in flight

    // per-row 1/rowsum (static-indexed registers)
#pragma unroll
    for (int i = 0; i < 8; ++i) {
      const f32x4 r0 = *(const f32x4*)&red[i][0];
      const f32x4 r1 = *(const f32x4*)&red[i][4];
      rinv[i] = 1.0f / (((r0[0] + r0[1]) + (r0[2] + r0[3])) +
                        ((r1[0] + r1[1]) + (r1[2] + r1[3])));
    }

    // ---- PV MFMA for block jj (stores interleaved only for the last) ----
    f32x4 acc[4];
#pragma unroll
    for (int g = 0; g < 4; ++g) acc[g] = (f32x4){0.f, 0.f, 0.f, 0.f};
#pragma unroll
    for (int i = 0; i < 8; ++i) {
#pragma unroll
      for (int h = 0; h < 2; ++h) {
        const int t = 2 * i + h;
        const bf16x8 af = *(const bf16x8*)(
            pw + (lr8 << 10) + (((t << 6) + (kg << 4)) ^ (lr8 << 4)));
        const __bf16* vblk =
            vFb + ((size_t)((wave << 4) + t) << 11) + (lane << 3);
#pragma unroll
        for (int g = 0; g < 4; ++g) {
          const bf16x8 bf = *(const bf16x8*)(vblk + (g << 9));
          acc[g] =
              __builtin_amdgcn_mfma_f32_16x16x32_bf16(af, bf, acc[g], 0, 0, 0);
        }
      }
      if (jj == 3) {   // last block: trickle its stores into the PV loop
        const int swz = i << 4;
        const bf16x4 qA =
            *(const bf16x4*)(pw + (i << 10) + (((lane << 3)) ^ swz));
        const bf16x4 qB =
            *(const bf16x4*)(pw + (i << 10) + ((512 + (lane << 3)) ^ swz));
        f32x4 oA, oB;
#pragma unroll
        for (int j = 0; j < 4; ++j) {
          oA[j] = (float)qA[j] * rinv[i];
          oB[j] = (float)qB[j] * rinv[i];
        }
        *(f32x4*)(attn_cur + (size_t)i * LL)       = oA;
        *(f32x4*)(attn_cur + (size_t)i * LL + 256) = oB;
      }
    }

    // ---- epilogue: 2-step cross-wave O reduction in osum4 (NOT pbuf:
    //      pbuf must survive into the next score phase) ----
    LGKM_BARRIER();   // osum4 free (prev readers passed); lgkm-only
    if (wave >= 4 && kg < 2) {
#pragma unroll
      for (int g = 0; g < 4; ++g)
#pragma unroll
        for (int ii = 0; ii < 4; ++ii)
          osum4[((wave - 4) * 8 + kg * 4 + ii) * 64 + g * 16 + lrow] =
              acc[g][ii];
    }
    LGKM_BARRIER();
    if (wave < 4 && kg < 2) {
#pragma unroll
      for (int g = 0; g < 4; ++g)
#pragma unroll
        for (int ii = 0; ii < 4; ++ii) {
          float* p = &osum4[(wave * 8 + kg * 4 + ii) * 64 + g * 16 + lrow];
          *p += acc[g][ii];
        }
    }
    LGKM_BARRIER();
    if (tid < 128) {
      const int orow = tid >> 4;          // 0..7
      const int d    = (tid & 15) << 2;   // 0,4,..,60
      f32x4 o = {0.f, 0.f, 0.f, 0.f};
#pragma unroll
      for (int w = 0; w < 4; ++w) {
        const f32x4 rr = *(const f32x4*)(osum4 + ((w * 8 + orow) << 6) + d);
#pragma unroll
        for (int j = 0; j < 4; ++j) o[j] += rr[j];
      }
      float rt = 0.f;   // runtime orow -> recompute from LDS red (rule #20)
#pragma unroll
      for (int w = 0; w < 8; ++w) rt += red[orow][w];
      const float rinv_o = 1.0f / rt;
#pragma unroll
      for (int j = 0; j < 4; ++j) o[j] *= rinv_o;
      *(f32x4*)(out + ((size_t)b * LL + row0 + orow) * DVV + d) = o;
    }

    attn_prev = attn_cur;   // hand off deferred-store target
  }
}

extern "C" void kernel_launch(void* const* d_in, const int* in_sizes, int n_in,
                              void* d_out, int out_size, void* d_ws,
                              size_t ws_size, hipStream_t stream) {
  (void)in_sizes; (void)n_in; (void)out_size; (void)ws_size;
  const float* v    = (const float*)d_in[0];
  const int*   mask = (const int*)d_in[1];
  const float* ra1  = (const float*)d_in[2];
  const float* ra2  = (const float*)d_in[3];
  // d_in[4] = len_q, always 4096 (shapes fixed) -> constants above

  float* out  = (float*)d_out;
  float* attn = out + (size_t)BB * LL * DVV;   // outputs concatenated

  __bf16* vF = (__bf16*)d_ws;                  // 2 MB fragment-linear V

  hipLaunchKernelGGL(prep_kernel, dim3(BB * (LL / 64)), dim3(256), 0, stream,
                     v, vF);
  hipLaunchKernelGGL(attn_main, dim3(512), dim3(512), 0, stream,
                     ra1, ra2, mask, vF, out, attn);
}

// Round 6
// 316.850 us; speedup vs baseline: 2.0635x; 2.0635x over previous
//
#include <hip/hip_runtime.h>
#include <hip/hip_bf16.h>

// Problem constants (fixed by reference): B=4, L=4096, R=8, DV=64
#define BB  4
#define LL  4096
#define RR  8
#define DVV 64

typedef __bf16 bf16x8 __attribute__((ext_vector_type(8)));
typedef __bf16 bf16x4 __attribute__((ext_vector_type(4)));
typedef float  f32x4  __attribute__((ext_vector_type(4)));
typedef int    i32x4  __attribute__((ext_vector_type(4)));

#define LGKM_BARRIER() \
  asm volatile("s_waitcnt lgkmcnt(0)\n\ts_barrier" ::: "memory")

// ---------------------------------------------------------------------------
// Pre-kernel (256 blocks x 256 thr): v[b][m][d] fp32 -> vF fragment-linear
// bf16 MFMA B-fragments (unit = (b, colblk32, dblk16); lane l holds
// V[colblk*32 + (l>>4)*8 + j][dblk*16 + (l&15)], 16B contiguous per lane).
// ---------------------------------------------------------------------------
__global__ __launch_bounds__(256) void prep_kernel(
    const float* __restrict__ v, __bf16* __restrict__ vF) {
  __shared__ __bf16 tl[64][72];
  const int blk = blockIdx.x;         // 256 blocks
  const int b   = blk >> 6;           // 64 tiles per batch
  const int m0  = (blk & 63) << 6;
  const int tid = threadIdx.x;

  const float* vb = v + (((size_t)(b * LL + m0)) << 6);
#pragma unroll
  for (int i = 0; i < 16; ++i) {
    const int idx = (i << 8) + tid;   // m = idx>>6, d = idx&63
    tl[idx & 63][idx >> 6] = (__bf16)vb[idx];
  }
  __syncthreads();

  const int wv = tid >> 6, ln = tid & 63;
#pragma unroll
  for (int i = 0; i < 2; ++i) {
    const int u  = wv + (i << 2);
    const int cb = u >> 2, gg = u & 3;
    const int d  = gg * 16 + (ln & 15);
    const int c  = cb * 32 + ((ln >> 4) << 3);
    const size_t unit = ((size_t)(b * 128 + (m0 >> 5) + cb) << 2) + gg;
    *(bf16x8*)(vF + (unit << 9) + (ln << 3)) = *(const bf16x8*)&tl[d][c];
  }
}

// ---------------------------------------------------------------------------
// Main kernel: 2048 WGs x 512 thr (8 waves), 64.25 KB LDS -> 2 WGs/CU.
// (Round-5 persistent/deferred structure REVERTED: its cross-block register
// carries spilled to scratch -> FETCH/WRITE +550 MB each, 430 us.)
// WG owns (b, 8 rows). COMPUTE ownership: wave owns 512 cols (score+PV,
// unchanged from round 4). STORE ownership (new): wave w stores ROW w
// entirely -- 16 consecutive 1KB chunks = 16 KB LINEAR per wave, 128 KB
// linear per WG, exactly the fill kernel's (6.4 TB/s-proven) stream shape.
// Rounds 0-4 stored with +16 KB row-stride jumps between chunks and all
// plateaued at 1.4-2.3 TB/s effective write BW; linearizing the stream is
// the single mechanism under test this round. Store data comes from
// cross-wave LDS reads; rinv is one wave-uniform scalar (pressure drops).
// One chunk trickles per PV t-iter. lgkm-only barriers keep stores in
// flight; LDS reads complete into VGPRs pre-barrier so pbuf reuse is safe.
// ---------------------------------------------------------------------------
__global__ __launch_bounds__(512, 4) void attn_main(
    const float* __restrict__ ra1, const float* __restrict__ ra2,
    const int* __restrict__ mask, const __bf16* __restrict__ vF,
    float* __restrict__ out, float* __restrict__ attn) {
  __shared__ __bf16 pbuf[8 * 8 * 512];    // 64 KB: [wave][row][col] bf16 e
  __shared__ float  red[8][8];            // [row][wave] partial row sums

  const int wg   = blockIdx.x;            // 0..2047
  const int b    = wg >> 9;               // 512 WGs per batch
  const int row0 = (wg & 511) << 3;       // 8 rows per WG
  const int tid  = threadIdx.x;
  const int wave = tid >> 6;              // 0..7
  const int lane = tid & 63;
  const int W    = wave << 9;             // wave's 512-col compute chunk

  // ---- one-time: ra2 (8r x 2x4 cols) + mask into registers ----
  const float* r2 = ra2 + (size_t)b * (RR * LL) + W + (lane << 2);
  f32x4 rA[RR], rB[RR];
#pragma unroll
  for (int r = 0; r < RR; ++r) {
    rA[r] = *(const f32x4*)(r2 + r * LL);
    rB[r] = *(const f32x4*)(r2 + r * LL + 256);
  }
  const int* mp = mask + (size_t)b * LL + W + (lane << 2);   // mask [B][1][L]
  const i32x4 mAv = *(const i32x4*)mp;
  const i32x4 mBv = *(const i32x4*)(mp + 256);
  f32x4 mA, mB;
#pragma unroll
  for (int j = 0; j < 4; ++j) {
    mA[j] = mAv[j] ? 1.0f : 0.0f;
    mB[j] = mBv[j] ? 1.0f : 0.0f;
  }

  const float* a_base = ra1 + ((size_t)b * LL + row0) * RR;
  char* const  pw     = (char*)pbuf + (wave << 13);   // wave's 8 KB slice

  // ---- score phase: s -> e=exp(s)*mask, bf16 e -> LDS, per-row partials ----
  float part[8];
#pragma unroll
  for (int i = 0; i < 8; ++i) {
    const float* ap = a_base + i * RR;   // row-uniform -> scalar loads
    f32x4 sA = {0.f, 0.f, 0.f, 0.f}, sB = {0.f, 0.f, 0.f, 0.f};
#pragma unroll
    for (int r = 0; r < RR; ++r) {
      const float a = ap[r];
#pragma unroll
      for (int j = 0; j < 4; ++j) {
        sA[j] = fmaf(a, rA[r][j], sA[j]);
        sB[j] = fmaf(a, rB[r][j], sB[j]);
      }
    }
    f32x4 eA, eB;
#pragma unroll
    for (int j = 0; j < 4; ++j) {
      eA[j] = __expf(sA[j]) * mA[j];   // |s| <= ~17: exp safe in fp32
      eB[j] = __expf(sB[j]) * mB[j];
    }
    part[i] = ((eA[0] + eA[1]) + (eA[2] + eA[3])) +
              ((eB[0] + eB[1]) + (eB[2] + eB[3]));

    bf16x4 pA, pB;
#pragma unroll
    for (int j = 0; j < 4; ++j) { pA[j] = (__bf16)eA[j]; pB[j] = (__bf16)eB[j]; }
    // XOR swizzle (byte bits 4-6 ^ row): pure per-row permutation of 16B
    // blocks; write pattern matched by both the PV b128 reads and the
    // cross-wave b64 store-chunk reads below.
    const int swz = (i & 7) << 4;
    *(bf16x4*)(pw + (i << 10) + (((lane << 3)) ^ swz))       = pA;
    *(bf16x4*)(pw + (i << 10) + ((512 + (lane << 3)) ^ swz)) = pB;
  }
  // 8 independent butterfly chains, interleaved -> latency pipelined
#pragma unroll
  for (int s = 1; s < 64; s <<= 1)
#pragma unroll
    for (int i = 0; i < 8; ++i) part[i] += __shfl_xor(part[i], s);
  if (lane == 0) {
#pragma unroll
    for (int i = 0; i < 8; ++i) red[i][wave] = part[i];
  }
  LGKM_BARRIER();   // pbuf + red complete (no global stores in flight yet)

  // ---- wave-uniform 1/rowsum for the row THIS wave will store ----
  float rs = 0.f;
#pragma unroll
  for (int v = 0; v < 8; ++v) rs += red[wave][v];
  const float rinv_w = 1.0f / rs;

  // ---- fused PV MFMA + linear-stream attn stores (one 1KB chunk / t) ----
  const int lrow = lane & 15, kg = lane >> 4;
  const int lr8  = lrow & 7;              // A rows 8-15 duplicate rows 0-7
  f32x4 acc[4];
#pragma unroll
  for (int g = 0; g < 4; ++g) acc[g] = (f32x4){0.f, 0.f, 0.f, 0.f};
  const __bf16* vFb = vF + ((size_t)b << 18);
  // wave w stores row (row0+w): fully linear 16 KB
  float* arow = attn + ((size_t)b * LL + row0 + wave) * LL;

#pragma unroll
  for (int t = 0; t < 16; ++t) {
    const bf16x8 af = *(const bf16x8*)(
        pw + (lr8 << 10) + (((t << 6) + (kg << 4)) ^ (lr8 << 4)));
    const __bf16* vblk =
        vFb + ((size_t)((wave << 4) + t) << 11) + (lane << 3);
#pragma unroll
    for (int g = 0; g < 4; ++g) {
      const bf16x8 bf = *(const bf16x8*)(vblk + (g << 9));
      acc[g] =
          __builtin_amdgcn_mfma_f32_16x16x32_bf16(af, bf, acc[g], 0, 0, 0);
    }
    // store chunk t of row (row0+wave): cols [t*256, t*256+256).
    // e lives in owner-wave (t>>1)'s slice, row index = wave, half = t&1.
    const bf16x4 q = *(const bf16x4*)(
        (const char*)pbuf + ((t >> 1) << 13) + (wave << 10) + ((t & 1) << 9) +
        ((lane << 3) ^ ((wave & 7) << 4)));
    f32x4 o;
#pragma unroll
    for (int j = 0; j < 4; ++j) o[j] = (float)q[j] * rinv_w;
    *(f32x4*)(arow + (t << 8) + (lane << 2)) = o;
  }

  // ---- cross-wave O reduction: reuse pbuf (store-chunk LDS reads already
  //      retired into VGPRs); lgkm-only barriers keep global stores in
  //      flight ----
  LGKM_BARRIER();
  float* osum = (float*)pbuf;   // [8 waves][8 rows][64 d] fp32 = 16 KB
  // C/D layout: row = kg*4 + ii (valid rows 0-7 -> kg<2), col = g*16 + lrow
  if (kg < 2) {
#pragma unroll
    for (int g = 0; g < 4; ++g)
#pragma unroll
      for (int ii = 0; ii < 4; ++ii)
        osum[(wave * 8 + kg * 4 + ii) * 64 + g * 16 + lrow] = acc[g][ii];
  }
  LGKM_BARRIER();

  if (tid < 128) {
    const int orow = tid >> 4;          // 0..7
    const int d    = (tid & 15) << 2;   // 0,4,..,60
    f32x4 o = {0.f, 0.f, 0.f, 0.f};
#pragma unroll
    for (int w = 0; w < 8; ++w) {
      const f32x4 rr = *(const f32x4*)(osum + ((w * 8 + orow) << 6) + d);
#pragma unroll
      for (int j = 0; j < 4; ++j) o[j] += rr[j];
    }
    float rt = 0.f;
#pragma unroll
    for (int w = 0; w < 8; ++w) rt += red[orow][w];
    const float rinv_o = 1.0f / rt;   // deferred normalization of PV
#pragma unroll
    for (int j = 0; j < 4; ++j) o[j] *= rinv_o;
    *(f32x4*)(out + ((size_t)b * LL + row0 + orow) * DVV + d) = o;
  }
}

extern "C" void kernel_launch(void* const* d_in, const int* in_sizes, int n_in,
                              void* d_out, int out_size, void* d_ws,
                              size_t ws_size, hipStream_t stream) {
  (void)in_sizes; (void)n_in; (void)out_size; (void)ws_size;
  const float* v    = (const float*)d_in[0];
  const int*   mask = (const int*)d_in[1];
  const float* ra1  = (const float*)d_in[2];
  const float* ra2  = (const float*)d_in[3];
  // d_in[4] = len_q, always 4096 (shapes fixed) -> constants above

  float* out  = (float*)d_out;
  float* attn = out + (size_t)BB * LL * DVV;   // outputs concatenated

  __bf16* vF = (__bf16*)d_ws;                  // 2 MB fragment-linear V

  hipLaunchKernelGGL(prep_kernel, dim3(BB * (LL / 64)), dim3(256), 0, stream,
                     v, vF);
  hipLaunchKernelGGL(attn_main, dim3(BB * LL / 8), dim3(512), 0, stream,
                     ra1, ra2, mask, vF, out, attn);
}